// Round 1
// baseline (5447.163 us; speedup 1.0000x reference)
//
#include <hip/hip_runtime.h>
#include <hip/hip_bf16.h>
#include <cstddef>

// Problem constants
#define BB 4
#define KK 32      // KMOD
#define TTT 64     // T
#define NNC 128    // N
#define GG4 512    // 4N
// X: [B=4][K=32][T=64][N=128] = 1048576 floats
// h: [inst][b][s][2N], max 64*4*32*256 = 2097152 floats (same as 32*4*64*256)
// red: [b][64 chunks][2] = 512 floats

__global__ void k_copy(const float4* __restrict__ src, float4* __restrict__ dst, int n4) {
    int i = blockIdx.x * blockDim.x + threadIdx.x;
    if (i < n4) dst[i] = src[i];
}

// Per-batch partial sums for GroupNorm: grid = B*64 blocks, 256 threads, 4096 floats/block
__global__ void k_gnred(const float* __restrict__ X, float* __restrict__ red) {
    int b = blockIdx.x >> 6, chunk = blockIdx.x & 63;
    const float4* p4 = (const float4*)(X + (size_t)b * 262144 + (size_t)chunk * 4096);
    float s = 0.f, ss = 0.f;
#pragma unroll
    for (int i = 0; i < 4; ++i) {
        float4 v = p4[threadIdx.x + i * 256];
        s  += v.x + v.y + v.z + v.w;
        ss += v.x * v.x + v.y * v.y + v.z * v.z + v.w * v.w;
    }
    for (int off = 32; off; off >>= 1) {
        s  += __shfl_down(s, off);
        ss += __shfl_down(ss, off);
    }
    __shared__ float l0[4], l1[4];
    int w = threadIdx.x >> 6;
    if ((threadIdx.x & 63) == 0) { l0[w] = s; l1[w] = ss; }
    __syncthreads();
    if (threadIdx.x == 0) {
        float a = l0[0] + l0[1] + l0[2] + l0[3];
        float c = l1[0] + l1[1] + l1[2] + l1[3];
        red[(b * 64 + chunk) * 2]     = a;
        red[(b * 64 + chunk) * 2 + 1] = c;
    }
}

__device__ __forceinline__ float sigm(float x) { return 1.f / (1.f + __expf(-x)); }
__device__ __forceinline__ float tanh_fast(float x) {
    x = fminf(fmaxf(x, -15.f), 15.f);
    float e = __expf(2.f * x);
    return (e - 1.f) / (e + 1.f);
}

// Fused: GroupNorm-apply + input projection (pre) + BiLSTM scan.
// One workgroup per (inst, dir, b). 512 threads; thread g owns gate row g.
template <bool BAND>
__global__ __launch_bounds__(512, 2) void k_scan(
    const float* __restrict__ X, float* __restrict__ hout,
    const float* __restrict__ red,
    const float* __restrict__ w_ih, const float* __restrict__ w_hh,
    const float* __restrict__ b_ih, const float* __restrict__ b_hh,
    const float* __restrict__ gn_g, const float* __restrict__ gn_b,
    int layer)
{
    constexpr int S    = BAND ? 32 : 64;   // sequence length
    constexpr int INST = BAND ? 64 : 32;   // # instances
    const int tid  = threadIdx.x;          // gate row g in [0,512)
    const int bid  = blockIdx.x;
    const int b    = bid & 3;
    const int dir  = (bid >> 2) & 1;
    const int inst = bid >> 3;

    __shared__ float xn[S * 128];
    __shared__ float hbuf[128];
    __shared__ float gbuf[512];

    // mean / rstd from partials (redundant per thread; L1-cached)
    float s0 = 0.f, s1 = 0.f;
    {
        const float* rp = red + b * 128;
#pragma unroll 16
        for (int i = 0; i < 128; i += 2) { s0 += rp[i]; s1 += rp[i + 1]; }
    }
    const float mu = s0 * (1.0f / 262144.0f);
    const float rs = rsqrtf(fmaxf(s1 * (1.0f / 262144.0f) - mu * mu, 0.f) + 1e-5f);

    // normalize this WG's x-slice into LDS
    {
        const size_t xbase = BAND ? ((size_t)b * 2048 + inst) * 128
                                  : ((size_t)b * 32 + inst) * 64 * 128;
        const float* gmg = gn_g + layer * 128;
        const float* gmb = gn_b + layer * 128;
        for (int i4 = tid; i4 < S * 32; i4 += 512) {
            int srow = i4 >> 5, n4 = i4 & 31;
            const float4 v = *(const float4*)(X + xbase +
                              (BAND ? (size_t)srow * 8192 : (size_t)srow * 128) + n4 * 4);
            const float4 ga = *(const float4*)(gmg + n4 * 4);
            const float4 be = *(const float4*)(gmb + n4 * 4);
            float4 o;
            o.x = (v.x - mu) * rs * ga.x + be.x;
            o.y = (v.y - mu) * rs * ga.y + be.y;
            o.z = (v.z - mu) * rs * ga.z + be.z;
            o.w = (v.w - mu) * rs * ga.w + be.w;
            *(float4*)(xn + srow * 128 + n4 * 4) = o;
        }
    }
    __syncthreads();

    const size_t wbase = ((size_t)layer * INST + inst) * 2 + dir;
    float w[128];

    // ---- input projection: pre_r[st] = bias + w_ih[g,:] . xn[sidx,:] ----
    {
        const float* wr = w_ih + (wbase * 512 + tid) * 128;
#pragma unroll
        for (int j = 0; j < 32; ++j) {
            float4 v = *(const float4*)(wr + 4 * j);
            w[4 * j] = v.x; w[4 * j + 1] = v.y; w[4 * j + 2] = v.z; w[4 * j + 3] = v.w;
        }
    }
    const float bias = b_ih[wbase * 512 + tid] + b_hh[wbase * 512 + tid];

    float pre_r[S];
#pragma unroll
    for (int st = 0; st < S; ++st) {
        const int sidx = dir ? (S - 1 - st) : st;
        float acc = bias;
        const float* xr = xn + sidx * 128;
#pragma unroll
        for (int j = 0; j < 32; ++j) {
            float4 hv = *(const float4*)(xr + 4 * j);
            acc += w[4 * j] * hv.x + w[4 * j + 1] * hv.y
                 + w[4 * j + 2] * hv.z + w[4 * j + 3] * hv.w;
        }
        pre_r[st] = acc;
    }

    // ---- load recurrent weights (overwrite w) ----
    {
        const float* wr = w_hh + (wbase * 512 + tid) * 128;
#pragma unroll
        for (int j = 0; j < 32; ++j) {
            float4 v = *(const float4*)(wr + 4 * j);
            w[4 * j] = v.x; w[4 * j + 1] = v.y; w[4 * j + 2] = v.z; w[4 * j + 3] = v.w;
        }
    }

    if (tid < 128) hbuf[tid] = 0.f;
    float c = 0.f;
    __syncthreads();

    float* hob = hout + ((size_t)inst * 4 + b) * S * 256 + dir * 128;

    // ---- scan ----
#pragma unroll
    for (int st = 0; st < S; ++st) {
        float acc = pre_r[st];
#pragma unroll
        for (int j = 0; j < 32; ++j) {
            float4 hv = *(const float4*)(hbuf + 4 * j);   // broadcast read
            acc += w[4 * j] * hv.x + w[4 * j + 1] * hv.y
                 + w[4 * j + 2] * hv.z + w[4 * j + 3] * hv.w;
        }
        gbuf[tid] = acc;
        __syncthreads();
        if (tid < 128) {
            const float gi = gbuf[tid];
            const float gf = gbuf[tid + 128];
            const float gg = gbuf[tid + 256];
            const float go = gbuf[tid + 384];
            c = sigm(gf) * c + sigm(gi) * tanh_fast(gg);
            const float h = sigm(go) * tanh_fast(c);
            hbuf[tid] = h;
            const int sidx = dir ? (S - 1 - st) : st;
            hob[(size_t)sidx * 256 + tid] = h;
        }
        __syncthreads();
    }
}

// FC (h[2N] -> N) + bias + residual into X. Block = (inst, 8-row chunk), 256 thr.
template <bool BAND>
__global__ void k_fc(const float* __restrict__ h, const float* __restrict__ fc_w,
                     const float* __restrict__ fc_b, float* __restrict__ X, int layer)
{
    constexpr int S    = BAND ? 32 : 64;
    constexpr int INST = BAND ? 64 : 32;
    constexpr int RPB  = 8;                       // rows per block
    const int inst  = blockIdx.x / (BB * S / RPB);
    const int chunk = blockIdx.x % (BB * S / RPB);

    __shared__ float hs[RPB * 256];
    const int tid = threadIdx.x;
    const float* hbase = h + ((size_t)inst * BB * S + chunk * RPB) * 256;
    for (int i = tid; i < RPB * 64; i += 256)
        ((float4*)hs)[i] = ((const float4*)hbase)[i];
    __syncthreads();

    const int n  = tid & 127;
    const int rg = tid >> 7;                      // 0..1 -> rows rg*4 .. rg*4+3
    const float* wrow = fc_w + (((size_t)layer * INST + inst) * 128 + n) * 256;
    float a0 = 0.f, a1 = 0.f, a2 = 0.f, a3 = 0.f;
#pragma unroll 8
    for (int d4 = 0; d4 < 64; ++d4) {
        float4 wv = ((const float4*)wrow)[d4];
        float4 h0 = ((const float4*)(hs + (rg * 4 + 0) * 256))[d4];
        float4 h1 = ((const float4*)(hs + (rg * 4 + 1) * 256))[d4];
        float4 h2 = ((const float4*)(hs + (rg * 4 + 2) * 256))[d4];
        float4 h3 = ((const float4*)(hs + (rg * 4 + 3) * 256))[d4];
        a0 += wv.x * h0.x + wv.y * h0.y + wv.z * h0.z + wv.w * h0.w;
        a1 += wv.x * h1.x + wv.y * h1.y + wv.z * h1.z + wv.w * h1.w;
        a2 += wv.x * h2.x + wv.y * h2.y + wv.z * h2.z + wv.w * h2.w;
        a3 += wv.x * h3.x + wv.y * h3.y + wv.z * h3.z + wv.w * h3.w;
    }
    const float bias = fc_b[((size_t)layer * INST + inst) * 128 + n];
    float acc[4] = {a0, a1, a2, a3};
#pragma unroll
    for (int i = 0; i < 4; ++i) {
        const int r = chunk * RPB + rg * 4 + i;
        const int b = r / S, s = r % S;
        const size_t xi = BAND ? (((size_t)b * 32 + s) * 64 + inst) * 128 + n
                               : (((size_t)b * 32 + inst) * 64 + s) * 128 + n;
        X[xi] += acc[i] + bias;
    }
}

// out[4][30][64][128] = X[:, :30, :, :]
__global__ void k_slice(const float* __restrict__ X, float* __restrict__ out) {
    int i = blockIdx.x * 256 + threadIdx.x;       // float4 index, 245760 total
    if (i >= 245760) return;
    int n4 = i & 31;
    int r  = i >> 5;
    int t  = r & 63;
    int bk = r >> 6;
    int k  = bk % 30, b = bk / 30;
    ((float4*)out)[i] = *(const float4*)(X + (((size_t)b * 32 + k) * 64 + t) * 128 + (size_t)n4 * 4);
}

extern "C" void kernel_launch(void* const* d_in, const int* in_sizes, int n_in,
                              void* d_out, int out_size, void* d_ws, size_t ws_size,
                              hipStream_t stream) {
    const float* x     = (const float*)d_in[0];
    const float* tw_ih = (const float*)d_in[1];
    const float* tw_hh = (const float*)d_in[2];
    const float* tb_ih = (const float*)d_in[3];
    const float* tb_hh = (const float*)d_in[4];
    const float* tfc_w = (const float*)d_in[5];
    const float* tfc_b = (const float*)d_in[6];
    const float* tgn_g = (const float*)d_in[7];
    const float* tgn_b = (const float*)d_in[8];
    const float* bw_ih = (const float*)d_in[9];
    const float* bw_hh = (const float*)d_in[10];
    const float* bb_ih = (const float*)d_in[11];
    const float* bb_hh = (const float*)d_in[12];
    const float* bfc_w = (const float*)d_in[13];
    const float* bfc_b = (const float*)d_in[14];
    const float* bgn_g = (const float*)d_in[15];
    const float* bgn_b = (const float*)d_in[16];

    float* X   = (float*)d_ws;                 // 1048576 floats
    float* h   = X + 1048576;                  // 2097152 floats
    float* red = h + 2097152;                  // 512 floats

    k_copy<<<1024, 256, 0, stream>>>((const float4*)x, (float4*)X, 262144);

    for (int layer = 0; layer < 2; ++layer) {
        // temporal module (per-band LSTM over T)
        k_gnred<<<256, 256, 0, stream>>>(X, red);
        k_scan<false><<<256, 512, 0, stream>>>(X, h, red, tw_ih, tw_hh, tb_ih, tb_hh,
                                               tgn_g, tgn_b, layer);
        k_fc<false><<<1024, 256, 0, stream>>>(h, tfc_w, tfc_b, X, layer);
        // band module (per-frame LSTM over K)
        k_gnred<<<256, 256, 0, stream>>>(X, red);
        k_scan<true><<<512, 512, 0, stream>>>(X, h, red, bw_ih, bw_hh, bb_ih, bb_hh,
                                              bgn_g, bgn_b, layer);
        k_fc<true><<<1024, 256, 0, stream>>>(h, bfc_w, bfc_b, X, layer);
    }

    k_slice<<<960, 256, 0, stream>>>(X, (float*)d_out);
}

// Round 2
// 943.546 us; speedup vs baseline: 5.7731x; 5.7731x over previous
//
#include <hip/hip_runtime.h>
#include <hip/hip_bf16.h>
#include <cstddef>

// Problem constants
#define BB 4
#define KK 32      // KMOD
#define TTT 64     // T
#define NNC 128    // N
#define GG4 512    // 4N
// ws layout (floats):
//   X   [4][32][64][128]            = 1048576
//   h   [inst][b][s][256]           = 2097152
//   red [4][64][2]                  = 512
//   pre [bid][st(scan order)][512]  = 8388608   (256 or 512 WGs, same total)

__global__ void k_copy(const float4* __restrict__ src, float4* __restrict__ dst, int n4) {
    int i = blockIdx.x * blockDim.x + threadIdx.x;
    if (i < n4) dst[i] = src[i];
}

// Per-batch partial sums for GroupNorm: grid = B*64 blocks, 256 threads, 4096 floats/block
__global__ void k_gnred(const float* __restrict__ X, float* __restrict__ red) {
    int b = blockIdx.x >> 6, chunk = blockIdx.x & 63;
    const float4* p4 = (const float4*)(X + (size_t)b * 262144 + (size_t)chunk * 4096);
    float s = 0.f, ss = 0.f;
#pragma unroll
    for (int i = 0; i < 4; ++i) {
        float4 v = p4[threadIdx.x + i * 256];
        s  += v.x + v.y + v.z + v.w;
        ss += v.x * v.x + v.y * v.y + v.z * v.z + v.w * v.w;
    }
    for (int off = 32; off; off >>= 1) {
        s  += __shfl_down(s, off);
        ss += __shfl_down(ss, off);
    }
    __shared__ float l0[4], l1[4];
    int w = threadIdx.x >> 6;
    if ((threadIdx.x & 63) == 0) { l0[w] = s; l1[w] = ss; }
    __syncthreads();
    if (threadIdx.x == 0) {
        float a = l0[0] + l0[1] + l0[2] + l0[3];
        float c = l1[0] + l1[1] + l1[2] + l1[3];
        red[(b * 64 + chunk) * 2]     = a;
        red[(b * 64 + chunk) * 2 + 1] = c;
    }
}

__device__ __forceinline__ float sigm(float x) { return 1.f / (1.f + __expf(-x)); }
__device__ __forceinline__ float tanh_fast(float x) {
    x = fminf(fmaxf(x, -15.f), 15.f);
    float e = __expf(2.f * x);
    return (e - 1.f) / (e + 1.f);
}

// ---------------------------------------------------------------------------
// k_pre: GroupNorm-apply + input projection.
// WG per (inst, dir, b); 1024 threads = (gate g in [0,512), half h in {0,1}).
// Thread (g,h) holds a 64-float half-row of w_ih in 16 float4 regs (64 VGPR).
// Partials reduced via LDS every 4 steps; full pre (+bias) written to global
// in SCAN ORDER (dir reversal applied on the x side).
// ---------------------------------------------------------------------------
template <bool BAND>
__global__ __launch_bounds__(1024, 1) void k_pre(
    const float* __restrict__ X, float* __restrict__ pre,
    const float* __restrict__ red,
    const float* __restrict__ w_ih,
    const float* __restrict__ b_ih, const float* __restrict__ b_hh,
    const float* __restrict__ gn_g, const float* __restrict__ gn_b,
    int layer)
{
    constexpr int S    = BAND ? 32 : 64;
    constexpr int INST = BAND ? 64 : 32;
    const int tid = threadIdx.x;
    const int g   = tid & 511;
    const int hh  = tid >> 9;
    const int bid = blockIdx.x;
    const int b = bid & 3, dir = (bid >> 2) & 1, inst = bid >> 3;

    __shared__ float xn[S * 128];
    __shared__ float ex[4][1024];
    __shared__ float biasl[512];

    // mean / rstd from partials (uniform addresses -> scalar-cached)
    float s0 = 0.f, s1 = 0.f;
    {
        const float* rp = red + b * 128;
#pragma unroll 16
        for (int i = 0; i < 128; i += 2) { s0 += rp[i]; s1 += rp[i + 1]; }
    }
    const float mu = s0 * (1.0f / 262144.0f);
    const float rs = rsqrtf(fmaxf(s1 * (1.0f / 262144.0f) - mu * mu, 0.f) + 1e-5f);

    const size_t wbase = ((size_t)layer * INST + inst) * 2 + dir;
    if (tid < 512) biasl[tid] = b_ih[wbase * 512 + tid] + b_hh[wbase * 512 + tid];

    // normalize this WG's x-slice into LDS
    {
        const size_t xbase = BAND ? ((size_t)b * 2048 + inst) * 128
                                  : ((size_t)b * 32 + inst) * 64 * 128;
        const float* gmg = gn_g + layer * 128;
        const float* gmb = gn_b + layer * 128;
        for (int i4 = tid; i4 < S * 32; i4 += 1024) {
            int srow = i4 >> 5, n4 = i4 & 31;
            const float4 v = *(const float4*)(X + xbase +
                              (BAND ? (size_t)srow * 8192 : (size_t)srow * 128) + n4 * 4);
            const float4 ga = *(const float4*)(gmg + n4 * 4);
            const float4 be = *(const float4*)(gmb + n4 * 4);
            float4 o;
            o.x = (v.x - mu) * rs * ga.x + be.x;
            o.y = (v.y - mu) * rs * ga.y + be.y;
            o.z = (v.z - mu) * rs * ga.z + be.z;
            o.w = (v.w - mu) * rs * ga.w + be.w;
            *(float4*)(xn + srow * 128 + n4 * 4) = o;
        }
    }

    // half-row of w_ih: 16 float4 (64 VGPR), statically indexed
    float4 w4[16];
    {
        const float* wr = w_ih + (wbase * 512 + g) * 128 + hh * 64;
#pragma unroll
        for (int j = 0; j < 16; ++j) w4[j] = *(const float4*)(wr + 4 * j);
    }
    __syncthreads();

    float* pb = pre + (size_t)bid * (S * 512);
    for (int st0 = 0; st0 < S; st0 += 4) {
#pragma unroll
        for (int q = 0; q < 4; ++q) {
            const int st = st0 + q;
            const int sidx = dir ? (S - 1 - st) : st;
            const float* xr = xn + sidx * 128 + hh * 64;   // wave-uniform -> broadcast
            float acc = 0.f;
#pragma unroll
            for (int j = 0; j < 16; ++j) {
                float4 hv = *(const float4*)(xr + 4 * j);
                acc += w4[j].x * hv.x + w4[j].y * hv.y + w4[j].z * hv.z + w4[j].w * hv.w;
            }
            ex[q][hh * 512 + g] = acc;
        }
        __syncthreads();
        for (int idx = tid; idx < 4 * 512; idx += 1024) {
            int q = idx >> 9, gg = idx & 511;
            pb[(size_t)(st0 + q) * 512 + gg] = ex[q][gg] + ex[q][512 + gg] + biasl[gg];
        }
        __syncthreads();
    }
}

// ---------------------------------------------------------------------------
// k_scan2: the recurrence only. WG per (inst, dir, b); 1024 threads = (g, h).
// w_hh half-row in 16 float4 regs. pre staged from global into double-buffered
// LDS chunks of 8 steps with a register prefetch. Per step: half-dot -> LDS
// exchange -> 128 threads apply gates -> h broadcast from LDS.
// ---------------------------------------------------------------------------
template <bool BAND>
__global__ __launch_bounds__(1024, 1) void k_scan2(
    const float* __restrict__ pre, float* __restrict__ hout,
    const float* __restrict__ w_hh, int layer)
{
    constexpr int S    = BAND ? 32 : 64;
    constexpr int INST = BAND ? 64 : 32;
    constexpr int CH   = 8;
    const int tid = threadIdx.x;
    const int g   = tid & 511;
    const int hh  = tid >> 9;
    const int bid = blockIdx.x;
    const int b = bid & 3, dir = (bid >> 2) & 1, inst = bid >> 3;

    __shared__ float plds[2][CH * 512];
    __shared__ float ex[1024];
    __shared__ float hbuf[128];

    const size_t wbase = ((size_t)layer * INST + inst) * 2 + dir;
    float4 w4[16];
    {
        const float* wr = w_hh + (wbase * 512 + g) * 128 + hh * 64;
#pragma unroll
        for (int j = 0; j < 16; ++j) w4[j] = *(const float4*)(wr + 4 * j);
    }

    const float* pb = pre + (size_t)bid * (S * 512);
    ((float4*)plds[0])[tid] = ((const float4*)pb)[tid];   // chunk 0
    if (tid < 128) hbuf[tid] = 0.f;
    float c = 0.f;
    float4 pf = make_float4(0.f, 0.f, 0.f, 0.f);
    __syncthreads();

    float* hob = hout + ((size_t)inst * 4 + b) * S * 256 + dir * 128;

    for (int ch = 0; ch < S / CH; ++ch) {
        const int buf = ch & 1;
        if (ch + 1 < S / CH)
            pf = ((const float4*)(pb + (size_t)(ch + 1) * CH * 512))[tid];  // prefetch
#pragma unroll
        for (int q = 0; q < CH; ++q) {
            const float* hr = hbuf + hh * 64;              // wave-uniform -> broadcast
            float acc = (hh == 0) ? plds[buf][q * 512 + g] : 0.f;
#pragma unroll
            for (int j = 0; j < 16; ++j) {
                float4 hv = *(const float4*)(hr + 4 * j);
                acc += w4[j].x * hv.x + w4[j].y * hv.y + w4[j].z * hv.z + w4[j].w * hv.w;
            }
            ex[hh * 512 + g] = acc;
            __syncthreads();
            if (tid < 128) {
                const float gi = ex[tid]       + ex[512 + tid];
                const float gf = ex[128 + tid] + ex[640 + tid];
                const float gg = ex[256 + tid] + ex[768 + tid];
                const float go = ex[384 + tid] + ex[896 + tid];
                c = sigm(gf) * c + sigm(gi) * tanh_fast(gg);
                const float hv = sigm(go) * tanh_fast(c);
                hbuf[tid] = hv;
                const int st = ch * CH + q;
                const int sidx = dir ? (S - 1 - st) : st;
                hob[(size_t)sidx * 256 + tid] = hv;
            }
            __syncthreads();
        }
        if (ch + 1 < S / CH) {
            ((float4*)plds[buf ^ 1])[tid] = pf;
            __syncthreads();
        }
    }
}

// FC (h[2N] -> N) + bias + residual into X. Block = (inst, 8-row chunk), 256 thr.
template <bool BAND>
__global__ void k_fc(const float* __restrict__ h, const float* __restrict__ fc_w,
                     const float* __restrict__ fc_b, float* __restrict__ X, int layer)
{
    constexpr int S    = BAND ? 32 : 64;
    constexpr int INST = BAND ? 64 : 32;
    constexpr int RPB  = 8;                       // rows per block
    const int inst  = blockIdx.x / (BB * S / RPB);
    const int chunk = blockIdx.x % (BB * S / RPB);

    __shared__ float hs[RPB * 256];
    const int tid = threadIdx.x;
    const float* hbase = h + ((size_t)inst * BB * S + chunk * RPB) * 256;
    for (int i = tid; i < RPB * 64; i += 256)
        ((float4*)hs)[i] = ((const float4*)hbase)[i];
    __syncthreads();

    const int n  = tid & 127;
    const int rg = tid >> 7;                      // 0..1 -> rows rg*4 .. rg*4+3
    const float* wrow = fc_w + (((size_t)layer * INST + inst) * 128 + n) * 256;
    float a0 = 0.f, a1 = 0.f, a2 = 0.f, a3 = 0.f;
#pragma unroll 8
    for (int d4 = 0; d4 < 64; ++d4) {
        float4 wv = ((const float4*)wrow)[d4];
        float4 h0 = ((const float4*)(hs + (rg * 4 + 0) * 256))[d4];
        float4 h1 = ((const float4*)(hs + (rg * 4 + 1) * 256))[d4];
        float4 h2 = ((const float4*)(hs + (rg * 4 + 2) * 256))[d4];
        float4 h3 = ((const float4*)(hs + (rg * 4 + 3) * 256))[d4];
        a0 += wv.x * h0.x + wv.y * h0.y + wv.z * h0.z + wv.w * h0.w;
        a1 += wv.x * h1.x + wv.y * h1.y + wv.z * h1.z + wv.w * h1.w;
        a2 += wv.x * h2.x + wv.y * h2.y + wv.z * h2.z + wv.w * h2.w;
        a3 += wv.x * h3.x + wv.y * h3.y + wv.z * h3.z + wv.w * h3.w;
    }
    const float bias = fc_b[((size_t)layer * INST + inst) * 128 + n];
    float acc[4] = {a0, a1, a2, a3};
#pragma unroll
    for (int i = 0; i < 4; ++i) {
        const int r = chunk * RPB + rg * 4 + i;
        const int b = r / S, s = r % S;
        const size_t xi = BAND ? (((size_t)b * 32 + s) * 64 + inst) * 128 + n
                               : (((size_t)b * 32 + inst) * 64 + s) * 128 + n;
        X[xi] += acc[i] + bias;
    }
}

// out[4][30][64][128] = X[:, :30, :, :]
__global__ void k_slice(const float* __restrict__ X, float* __restrict__ out) {
    int i = blockIdx.x * 256 + threadIdx.x;       // float4 index, 245760 total
    if (i >= 245760) return;
    int n4 = i & 31;
    int r  = i >> 5;
    int t  = r & 63;
    int bk = r >> 6;
    int k  = bk % 30, b = bk / 30;
    ((float4*)out)[i] = *(const float4*)(X + (((size_t)b * 32 + k) * 64 + t) * 128 + (size_t)n4 * 4);
}

extern "C" void kernel_launch(void* const* d_in, const int* in_sizes, int n_in,
                              void* d_out, int out_size, void* d_ws, size_t ws_size,
                              hipStream_t stream) {
    const float* x     = (const float*)d_in[0];
    const float* tw_ih = (const float*)d_in[1];
    const float* tw_hh = (const float*)d_in[2];
    const float* tb_ih = (const float*)d_in[3];
    const float* tb_hh = (const float*)d_in[4];
    const float* tfc_w = (const float*)d_in[5];
    const float* tfc_b = (const float*)d_in[6];
    const float* tgn_g = (const float*)d_in[7];
    const float* tgn_b = (const float*)d_in[8];
    const float* bw_ih = (const float*)d_in[9];
    const float* bw_hh = (const float*)d_in[10];
    const float* bb_ih = (const float*)d_in[11];
    const float* bb_hh = (const float*)d_in[12];
    const float* bfc_w = (const float*)d_in[13];
    const float* bfc_b = (const float*)d_in[14];
    const float* bgn_g = (const float*)d_in[15];
    const float* bgn_b = (const float*)d_in[16];

    float* X   = (float*)d_ws;                 // 1048576 floats
    float* h   = X + 1048576;                  // 2097152 floats
    float* red = h + 2097152;                  // 512 floats
    float* pre = red + 512;                    // 8388608 floats

    k_copy<<<1024, 256, 0, stream>>>((const float4*)x, (float4*)X, 262144);

    for (int layer = 0; layer < 2; ++layer) {
        // temporal module (per-band LSTM over T)
        k_gnred<<<256, 256, 0, stream>>>(X, red);
        k_pre<false><<<256, 1024, 0, stream>>>(X, pre, red, tw_ih, tb_ih, tb_hh,
                                               tgn_g, tgn_b, layer);
        k_scan2<false><<<256, 1024, 0, stream>>>(pre, h, tw_hh, layer);
        k_fc<false><<<1024, 256, 0, stream>>>(h, tfc_w, tfc_b, X, layer);
        // band module (per-frame LSTM over K)
        k_gnred<<<256, 256, 0, stream>>>(X, red);
        k_pre<true><<<512, 1024, 0, stream>>>(X, pre, red, bw_ih, bb_ih, bb_hh,
                                              bgn_g, bgn_b, layer);
        k_scan2<true><<<512, 1024, 0, stream>>>(pre, h, bw_hh, layer);
        k_fc<true><<<1024, 256, 0, stream>>>(h, bfc_w, bfc_b, X, layer);
    }

    k_slice<<<960, 256, 0, stream>>>(X, (float*)d_out);
}